// Round 10
// baseline (157.747 us; speedup 1.0000x reference)
//
#include <hip/hip_runtime.h>

#define BB 4
#define CC 256
#define NN 4096

typedef __attribute__((ext_vector_type(8))) short bh8;
typedef __attribute__((ext_vector_type(4))) float f32x4;
typedef __attribute__((ext_vector_type(16))) float f32x16;

// workspace layout (bytes)
#define WPK_OFF  0                        // 20*8*64*8 bf16 = 163840 (B-frag packed W)
#define BALL_OFF 163840                   // 320 f32
#define QBF_OFF  165888                   // B*N*32 bf16 = 1 MB
#define KBF_OFF  (165888 + 1048576)
#define VBF_OFF  (165888 + 2097152)       // B*C*N bf16 = 8 MB

typedef const __attribute__((address_space(1))) void* gas_t;
typedef __attribute__((address_space(3))) void* las_t;
__device__ inline void gld16(const void* g, void* l) {
    __builtin_amdgcn_global_load_lds((gas_t)g, (las_t)l, 16, 0, 0);
}

__device__ inline int pack2bf(float a, float b) {
    unsigned ua = __builtin_bit_cast(unsigned, a) + 0x8000u;
    unsigned ub = __builtin_bit_cast(unsigned, b) + 0x8000u;
    return (int)__builtin_amdgcn_perm(ub, ua, 0x07060302u);
}
__device__ inline short f2bf1(float a) {
    return (short)((__builtin_bit_cast(unsigned, a) + 0x8000u) >> 16);
}

// ---------------- prep: Wpk B-fragments + ball (unchanged)
__global__ __launch_bounds__(256) void prep_w(const float* __restrict__ Wq,
        const float* __restrict__ bq, const float* __restrict__ Wk,
        const float* __restrict__ bk, const float* __restrict__ Wv,
        const float* __restrict__ bv, short* __restrict__ Wpk,
        float* __restrict__ ball) {
    int tid = blockIdx.x * 256 + threadIdx.x;
    if (tid < 10240) {
        int lane = tid & 63;
        int fc = tid >> 6;                 // mt*8 + ck
        int mt = fc >> 3, ck = fc & 7;
        int m = mt * 16 + (lane & 15);
        int c0 = ck * 32 + (lane >> 4) * 8;
        const float* wrow;
        if (m < 32)      wrow = Wq + m * 256;
        else if (m < 64) wrow = Wk + (m - 32) * 256;
        else             wrow = Wv + (m - 64) * 256;
        int d[4];
        #pragma unroll
        for (int p = 0; p < 4; ++p)
            d[p] = pack2bf(wrow[c0 + 2 * p], wrow[c0 + 2 * p + 1]);
        *(int4*)(Wpk + tid * 8) = make_int4(d[0], d[1], d[2], d[3]);
    }
    if (tid < 320) {
        float b2 = tid < 32 ? bq[tid] : (tid < 64 ? bk[tid - 32] : bv[tid - 64]);
        ball[tid] = b2;
    }
}

// ---------------- projections as MFMA GEMM (unchanged from R9 — A/B control;
// if this shows ~70 µs in top-5 next round, it becomes the target)
__global__ __launch_bounds__(256) void proj(const float* __restrict__ x,
        const short* __restrict__ Wpk, const float* __restrict__ ball,
        short* __restrict__ qbf, short* __restrict__ kbf,
        short* __restrict__ vbf) {
    __shared__ float xs[8192];             // 32 KB: x[256c][32n] fp32, granule-linear
    int t = threadIdx.x;
    int w = t >> 6, lane = t & 63, quad = lane >> 4, c15 = lane & 15;
    int b = blockIdx.x >> 7;
    int n0 = (blockIdx.x & 127) * 32;
    const float* xb = x + (size_t)b * CC * NN + n0;

    #pragma unroll
    for (int r = 0; r < 8; ++r) {
        const float* src = xb + (size_t)(w * 64 + r * 8 + (lane >> 3)) * NN + (lane & 7) * 4;
        gld16(src, (char*)xs + w * 8192 + r * 1024);
    }
    __syncthreads();

    int ns = w & 1, mh = w >> 1;           // n-sub, m-half
    int nb = ns * 16;

    bh8 af[8];
    #pragma unroll
    for (int ck = 0; ck < 8; ++ck) {
        float v[8];
        #pragma unroll
        for (int e = 0; e < 8; ++e)
            v[e] = xs[(ck * 32 + quad * 8 + e) * 32 + nb + c15];
        int d[4];
        #pragma unroll
        for (int p = 0; p < 4; ++p) d[p] = pack2bf(v[2 * p], v[2 * p + 1]);
        af[ck] = __builtin_bit_cast(bh8, make_int4(d[0], d[1], d[2], d[3]));
    }

    #pragma unroll
    for (int mpi = 0; mpi < 5; ++mpi) {
        int mtA = mh * 10 + mpi * 2, mtB = mtA + 1;
        float blA = ball[mtA * 16 + c15], blB = ball[mtB * 16 + c15];
        f32x4 accA = {blA, blA, blA, blA}, accB = {blB, blB, blB, blB};
        #pragma unroll
        for (int ck = 0; ck < 8; ++ck) {
            bh8 wfA = *(const bh8*)(Wpk + ((mtA * 8 + ck) * 64 + lane) * 8);
            bh8 wfB = *(const bh8*)(Wpk + ((mtB * 8 + ck) * 64 + lane) * 8);
            accA = __builtin_amdgcn_mfma_f32_16x16x32_bf16(af[ck], wfA, accA, 0, 0, 0);
            accB = __builtin_amdgcn_mfma_f32_16x16x32_bf16(af[ck], wfB, accB, 0, 0, 0);
        }
        #pragma unroll
        for (int half = 0; half < 2; ++half) {
            int mt = mtA + half;
            f32x4 acc = half ? accB : accA;
            if (mt < 4) {
                short* dst = (mt < 2) ? qbf : kbf;
                int m = (mt & 1) * 16 + c15;
                #pragma unroll
                for (int r = 0; r < 4; ++r)
                    dst[(size_t)(b * NN + n0 + nb + quad * 4 + r) * 32 + m] = f2bf1(acc[r]);
            } else {
                int c = mt * 16 + c15 - 64;
                int2 pk;
                pk.x = pack2bf(acc[0], acc[1]);
                pk.y = pack2bf(acc[2], acc[3]);
                *(int2*)(vbf + (size_t)b * CC * NN + (size_t)c * NN + n0 + nb + quad * 4) = pk;
            }
        }
    }
}

// ---------------- flash v5: producer/consumer specialization, 32x32 PV tiles
// block = 8 waves: w<4 producers (QK jsub=w, exp, P write, V staging),
// w>=4 consumers (PV: 64c x 64i via 4x mfma_32x32x16, acc=64 VGPR).
// grid 256 = 64 i-tiles x 4 b. Single barrier/step: producers build P[nxt] /
// stage V[nxt] while consumers eat P[cur] / V[cur].
__global__ __launch_bounds__(512, 1) void flash_attn(
        const short* __restrict__ qbf, const short* __restrict__ kbf,
        const short* __restrict__ vbf, const float* __restrict__ x,
        const float* __restrict__ gamma, float* __restrict__ out) {
    __shared__ char lds[82944];  // V 2x32KB @0 | P 2x8KB @65536 | lred 1KB @81920

    int bid = blockIdx.x;
    int b = bid & 3, i0 = (bid >> 2) * 64;  // batch pinned per-XCD (K/V L2)
    int t = threadIdx.x;
    int w = t >> 6, lane = t & 63, quad = lane >> 4, c15 = lane & 15;
    int l31 = lane & 31, l5 = lane >> 5;

    const short* kb = kbf + (size_t)b * NN * 32;
    const short* vb = vbf + (size_t)b * CC * NN;

    char* Pt = lds + 65536;
    float* lred = (float*)(lds + 81920);
    const f32x4 initc = {-12.f, -12.f, -12.f, -12.f};  // softmax shift in C

    if (w < 4) {
        // ================= producer =================
        const short* qb = qbf + (size_t)b * NN * 32;
        bh8 qf[4];
        #pragma unroll
        for (int is4 = 0; is4 < 4; ++is4)
            qf[is4] = *(const bh8*)(qb + (size_t)(i0 + is4 * 16 + c15) * 32 + quad * 8);
        const short* kptr = kb + (size_t)(w * 16 + c15) * 32 + quad * 8;
        // V staging: wave w covers rows [w*64, w*64+64), 8 gld16/step.
        // LDS dst WAVE-UNIFORM (HW: lane l -> base + l*16); granule XOR swizzle.
        const short* vsg = vb + (size_t)(w * 64 + (lane >> 3)) * NN
                              + ((lane & 7) ^ ((lane >> 3) & 7)) * 8;
        float lsum[4] = {0.f, 0.f, 0.f, 0.f};

        // prologue: stage V tile0 -> buf0; compute P0 -> Pbuf0
        #pragma unroll
        for (int r = 0; r < 8; ++r) gld16(vsg + r * 8 * NN, lds + w * 8192 + r * 1024);
        bh8 kf = *(const bh8*)kptr;
        {
            f32x4 sa[4];
            #pragma unroll
            for (int is4 = 0; is4 < 4; ++is4)
                sa[is4] = __builtin_amdgcn_mfma_f32_16x16x32_bf16(kf, qf[is4], initc, 0, 0, 0);
            kf = *(const bh8*)(kptr + 2048);   // K tile 1
            int jg = w * 2 + (quad >> 1);
            #pragma unroll
            for (int is4 = 0; is4 < 4; ++is4) {
                float p[4];
                #pragma unroll
                for (int r = 0; r < 4; ++r) { p[r] = __expf(sa[is4][r]); lsum[is4] += p[r]; }
                int i_ = is4 * 16 + c15;
                *(int2*)(Pt + i_ * 128 + ((jg ^ (i_ & 7)) * 16) + (quad & 1) * 8) =
                    make_int2(pack2bf(p[0], p[1]), pack2bf(p[2], p[3]));
            }
        }
        __syncthreads();   // publish P0, drain V0 DMA

        for (int jt = 0; jt < 64; ++jt) {
            if (jt < 63) {
                int nb_ = (jt + 1) & 1;
                f32x4 sa[4];
                #pragma unroll
                for (int is4 = 0; is4 < 4; ++is4)
                    sa[is4] = __builtin_amdgcn_mfma_f32_16x16x32_bf16(kf, qf[is4], initc, 0, 0, 0);
                kf = *(const bh8*)(kptr + (size_t)((jt + 2) & 63) * 2048);
                char* Pn = Pt + nb_ * 8192;
                int jg = w * 2 + (quad >> 1);
                #pragma unroll
                for (int is4 = 0; is4 < 4; ++is4) {
                    float p[4];
                    #pragma unroll
                    for (int r = 0; r < 4; ++r) { p[r] = __expf(sa[is4][r]); lsum[is4] += p[r]; }
                    int i_ = is4 * 16 + c15;
                    *(int2*)(Pn + i_ * 128 + ((jg ^ (i_ & 7)) * 16) + (quad & 1) * 8) =
                        make_int2(pack2bf(p[0], p[1]), pack2bf(p[2], p[3]));
                }
                // stage V tile jt+1 -> buf nb_ (consumers are on buf jt&1)
                const short* vs = vsg + (size_t)(jt + 1) * 64;
                char* vd = lds + nb_ * 32768 + w * 8192;
                #pragma unroll
                for (int r = 0; r < 8; ++r) gld16(vs + r * 8 * NN, vd + r * 1024);
            }
            __syncthreads();
        }
        // softmax denominators: quad-reduce, publish per-producer partials
        #pragma unroll
        for (int is4 = 0; is4 < 4; ++is4) {
            lsum[is4] += __shfl_xor(lsum[is4], 16);
            lsum[is4] += __shfl_xor(lsum[is4], 32);
        }
        if (lane < 16) {
            #pragma unroll
            for (int is4 = 0; is4 < 4; ++is4)
                lred[w * 64 + is4 * 16 + lane] = lsum[is4];
        }
        __syncthreads();
        // producers done
    } else {
        // ================= consumer =================
        int cw = w - 4;                    // c-range [cw*64, cw*64+64)
        f32x16 a00, a01, a10, a11;
        #pragma unroll
        for (int r = 0; r < 16; ++r) { a00[r] = 0.f; a01[r] = 0.f; a10[r] = 0.f; a11[r] = 0.f; }

        __syncthreads();   // match producer prologue barrier

        int swz = l31 & 7;
        int rowV0 = (cw * 64 + l31) * 128, rowV1 = rowV0 + 32 * 128;
        int rowP0 = l31 * 128, rowP1 = rowP0 + 32 * 128;
        for (int jt = 0; jt < 64; ++jt) {
            const char* Vb = lds + (jt & 1) * 32768;
            const char* Pc = Pt + (jt & 1) * 8192;
            #pragma unroll
            for (int kk = 0; kk < 4; ++kk) {
                int sl = ((kk * 2 + l5) ^ swz) * 16;
                bh8 va0 = *(const bh8*)(Vb + rowV0 + sl);
                bh8 va1 = *(const bh8*)(Vb + rowV1 + sl);
                bh8 pb0 = *(const bh8*)(Pc + rowP0 + sl);
                bh8 pb1 = *(const bh8*)(Pc + rowP1 + sl);
                a00 = __builtin_amdgcn_mfma_f32_32x32x16_bf16(va0, pb0, a00, 0, 0, 0);
                a01 = __builtin_amdgcn_mfma_f32_32x32x16_bf16(va0, pb1, a01, 0, 0, 0);
                a10 = __builtin_amdgcn_mfma_f32_32x32x16_bf16(va1, pb0, a10, 0, 0, 0);
                a11 = __builtin_amdgcn_mfma_f32_32x32x16_bf16(va1, pb1, a11, 0, 0, 0);
            }
            __syncthreads();
        }
        __syncthreads();   // match producer lred barrier

        // epilogue: O scale + residual + store (C/D 32x32: col=l31, row=(r&3)+8*(r>>2)+4*l5)
        float gm = gamma[0];
        const float* xb2 = x + (size_t)b * CC * NN;
        float* ob = out + (size_t)b * CC * NN;
        #pragma unroll
        for (int is = 0; is < 2; ++is) {
            int i_l = is * 32 + l31;
            float lt = lred[i_l] + lred[64 + i_l] + lred[128 + i_l] + lred[192 + i_l];
            float gl = gm / lt;
            int i = i0 + i_l;
            #pragma unroll
            for (int cs = 0; cs < 2; ++cs) {
                f32x16 av = (cs == 0) ? (is == 0 ? a00 : a01) : (is == 0 ? a10 : a11);
                #pragma unroll
                for (int r = 0; r < 16; ++r) {
                    int c = cw * 64 + cs * 32 + (r & 3) + 8 * (r >> 2) + 4 * l5;
                    ob[(size_t)c * NN + i] = gl * av[r] + xb2[(size_t)c * NN + i];
                }
            }
        }
    }
}

extern "C" void kernel_launch(void* const* d_in, const int* in_sizes, int n_in,
                              void* d_out, int out_size, void* d_ws, size_t ws_size,
                              hipStream_t stream) {
    const float* x     = (const float*)d_in[0];
    const float* Wq    = (const float*)d_in[1];
    const float* bq    = (const float*)d_in[2];
    const float* Wk    = (const float*)d_in[3];
    const float* bk    = (const float*)d_in[4];
    const float* Wv    = (const float*)d_in[5];
    const float* bv    = (const float*)d_in[6];
    const float* gamma = (const float*)d_in[7];
    float* out = (float*)d_out;
    char*  ws  = (char*)d_ws;
    short* Wpk  = (short*)(ws + WPK_OFF);
    float* ball = (float*)(ws + BALL_OFF);
    short* qbf  = (short*)(ws + QBF_OFF);
    short* kbf  = (short*)(ws + KBF_OFF);
    short* vbf  = (short*)(ws + VBF_OFF);

    prep_w<<<40, 256, 0, stream>>>(Wq, bq, Wk, bk, Wv, bv, Wpk, ball);
    proj<<<512, 256, 0, stream>>>(x, Wpk, ball, qbf, kbf, vbf);
    flash_attn<<<256, 512, 0, stream>>>(qbf, kbf, vbf, x, gamma, out);
}

// Round 11
// 157.650 us; speedup vs baseline: 1.0006x; 1.0006x over previous
//
#include <hip/hip_runtime.h>

#define BB 4
#define CC 256
#define NN 4096

typedef __attribute__((ext_vector_type(8))) short bh8;
typedef __attribute__((ext_vector_type(4))) float f32x4;
typedef __attribute__((ext_vector_type(16))) float f32x16;

// workspace layout (bytes)
#define WPK_OFF  0                        // 20*8*64*8 bf16 = 163840 (B-frag packed W)
#define BALL_OFF 163840                   // 320 f32
#define QBF_OFF  165888                   // B*N*32 bf16 = 1 MB
#define KBF_OFF  (165888 + 1048576)
#define VBF_OFF  (165888 + 2097152)       // B*C*N bf16 = 8 MB

typedef const __attribute__((address_space(1))) void* gas_t;
typedef __attribute__((address_space(3))) void* las_t;
__device__ inline void gld16(const void* g, void* l) {
    __builtin_amdgcn_global_load_lds((gas_t)g, (las_t)l, 16, 0, 0);
}

__device__ inline int pack2bf(float a, float b) {
    unsigned ua = __builtin_bit_cast(unsigned, a) + 0x8000u;
    unsigned ub = __builtin_bit_cast(unsigned, b) + 0x8000u;
    return (int)__builtin_amdgcn_perm(ub, ua, 0x07060302u);
}
__device__ inline short f2bf1(float a) {
    return (short)((__builtin_bit_cast(unsigned, a) + 0x8000u) >> 16);
}

// ---------------- prep: Wpk B-fragments + ball (unchanged)
__global__ __launch_bounds__(256) void prep_w(const float* __restrict__ Wq,
        const float* __restrict__ bq, const float* __restrict__ Wk,
        const float* __restrict__ bk, const float* __restrict__ Wv,
        const float* __restrict__ bv, short* __restrict__ Wpk,
        float* __restrict__ ball) {
    int tid = blockIdx.x * 256 + threadIdx.x;
    if (tid < 10240) {
        int lane = tid & 63;
        int fc = tid >> 6;                 // mt*8 + ck
        int mt = fc >> 3, ck = fc & 7;
        int m = mt * 16 + (lane & 15);
        int c0 = ck * 32 + (lane >> 4) * 8;
        const float* wrow;
        if (m < 32)      wrow = Wq + m * 256;
        else if (m < 64) wrow = Wk + (m - 32) * 256;
        else             wrow = Wv + (m - 64) * 256;
        int d[4];
        #pragma unroll
        for (int p = 0; p < 4; ++p)
            d[p] = pack2bf(wrow[c0 + 2 * p], wrow[c0 + 2 * p + 1]);
        *(int4*)(Wpk + tid * 8) = make_int4(d[0], d[1], d[2], d[3]);
    }
    if (tid < 320) {
        float b2 = tid < 32 ? bq[tid] : (tid < 64 ? bk[tid - 32] : bv[tid - 64]);
        ball[tid] = b2;
    }
}

// ---------------- projections as MFMA GEMM (unchanged — control variable)
__global__ __launch_bounds__(256) void proj(const float* __restrict__ x,
        const short* __restrict__ Wpk, const float* __restrict__ ball,
        short* __restrict__ qbf, short* __restrict__ kbf,
        short* __restrict__ vbf) {
    __shared__ float xs[8192];             // 32 KB: x[256c][32n] fp32, granule-linear
    int t = threadIdx.x;
    int w = t >> 6, lane = t & 63, quad = lane >> 4, c15 = lane & 15;
    int b = blockIdx.x >> 7;
    int n0 = (blockIdx.x & 127) * 32;
    const float* xb = x + (size_t)b * CC * NN + n0;

    #pragma unroll
    for (int r = 0; r < 8; ++r) {
        const float* src = xb + (size_t)(w * 64 + r * 8 + (lane >> 3)) * NN + (lane & 7) * 4;
        gld16(src, (char*)xs + w * 8192 + r * 1024);
    }
    __syncthreads();

    int ns = w & 1, mh = w >> 1;           // n-sub, m-half
    int nb = ns * 16;

    bh8 af[8];
    #pragma unroll
    for (int ck = 0; ck < 8; ++ck) {
        float v[8];
        #pragma unroll
        for (int e = 0; e < 8; ++e)
            v[e] = xs[(ck * 32 + quad * 8 + e) * 32 + nb + c15];
        int d[4];
        #pragma unroll
        for (int p = 0; p < 4; ++p) d[p] = pack2bf(v[2 * p], v[2 * p + 1]);
        af[ck] = __builtin_bit_cast(bh8, make_int4(d[0], d[1], d[2], d[3]));
    }

    #pragma unroll
    for (int mpi = 0; mpi < 5; ++mpi) {
        int mtA = mh * 10 + mpi * 2, mtB = mtA + 1;
        float blA = ball[mtA * 16 + c15], blB = ball[mtB * 16 + c15];
        f32x4 accA = {blA, blA, blA, blA}, accB = {blB, blB, blB, blB};
        #pragma unroll
        for (int ck = 0; ck < 8; ++ck) {
            bh8 wfA = *(const bh8*)(Wpk + ((mtA * 8 + ck) * 64 + lane) * 8);
            bh8 wfB = *(const bh8*)(Wpk + ((mtB * 8 + ck) * 64 + lane) * 8);
            accA = __builtin_amdgcn_mfma_f32_16x16x32_bf16(af[ck], wfA, accA, 0, 0, 0);
            accB = __builtin_amdgcn_mfma_f32_16x16x32_bf16(af[ck], wfB, accB, 0, 0, 0);
        }
        #pragma unroll
        for (int half = 0; half < 2; ++half) {
            int mt = mtA + half;
            f32x4 acc = half ? accB : accA;
            if (mt < 4) {
                short* dst = (mt < 2) ? qbf : kbf;
                int m = (mt & 1) * 16 + c15;
                #pragma unroll
                for (int r = 0; r < 4; ++r)
                    dst[(size_t)(b * NN + n0 + nb + quad * 4 + r) * 32 + m] = f2bf1(acc[r]);
            } else {
                int c = mt * 16 + c15 - 64;
                int2 pk;
                pk.x = pack2bf(acc[0], acc[1]);
                pk.y = pack2bf(acc[2], acc[3]);
                *(int2*)(vbf + (size_t)b * CC * NN + (size_t)c * NN + n0 + nb + quad * 4) = pk;
            }
        }
    }
}

// ---------------- flash v5.1: producer/consumer, CORRECTED DMA timing
// block = 8 waves: w<4 producers (QK jsub=w, exp, P write, V staging),
// w>=4 consumers (PV: 64c x 64i via 4x mfma_32x32x16).
// Protocol per step jt (all waves between barrier jt and barrier jt+1):
//   producers: issue V(jt+1)-DMA FIRST (max slack before the vmcnt(0) drain
//   at barrier jt+1), then compute P(jt+1) -> Pbuf[nxt];
//   consumers: eat V[cur], P[cur].
__global__ __launch_bounds__(512, 1) void flash_attn(
        const short* __restrict__ qbf, const short* __restrict__ kbf,
        const short* __restrict__ vbf, const float* __restrict__ x,
        const float* __restrict__ gamma, float* __restrict__ out) {
    __shared__ char lds[82944];  // V 2x32KB @0 | P 2x8KB @65536 | lred 1KB @81920

    int bid = blockIdx.x;
    int b = bid & 3, i0 = (bid >> 2) * 64;  // batch pinned per-XCD (K/V L2)
    int t = threadIdx.x;
    int w = t >> 6, lane = t & 63, quad = lane >> 4, c15 = lane & 15;
    int l31 = lane & 31, l5 = lane >> 5;

    const short* kb = kbf + (size_t)b * NN * 32;
    const short* vb = vbf + (size_t)b * CC * NN;

    char* Pt = lds + 65536;
    float* lred = (float*)(lds + 81920);
    const f32x4 initc = {-12.f, -12.f, -12.f, -12.f};  // softmax shift in C

    if (w < 4) {
        // ================= producer =================
        const short* qb = qbf + (size_t)b * NN * 32;
        bh8 qf[4];
        #pragma unroll
        for (int is4 = 0; is4 < 4; ++is4)
            qf[is4] = *(const bh8*)(qb + (size_t)(i0 + is4 * 16 + c15) * 32 + quad * 8);
        const short* kptr = kb + (size_t)(w * 16 + c15) * 32 + quad * 8;
        // V staging: wave w covers rows [w*64, w*64+64), 8 gld16/step.
        // LDS dst WAVE-UNIFORM (HW: lane l -> base + l*16); granule XOR swizzle.
        const short* vsg = vb + (size_t)(w * 64 + (lane >> 3)) * NN
                              + ((lane & 7) ^ ((lane >> 3) & 7)) * 8;
        float lsum[4] = {0.f, 0.f, 0.f, 0.f};

        // prologue: stage V tile0 -> buf0 FIRST, then compute P0 -> Pbuf0
        #pragma unroll
        for (int r = 0; r < 8; ++r) gld16(vsg + r * 8 * NN, lds + w * 8192 + r * 1024);
        bh8 kf = *(const bh8*)kptr;
        {
            f32x4 sa[4];
            #pragma unroll
            for (int is4 = 0; is4 < 4; ++is4)
                sa[is4] = __builtin_amdgcn_mfma_f32_16x16x32_bf16(kf, qf[is4], initc, 0, 0, 0);
            kf = *(const bh8*)(kptr + 2048);   // K tile 1
            int jg = w * 2 + (quad >> 1);
            #pragma unroll
            for (int is4 = 0; is4 < 4; ++is4) {
                float p[4];
                #pragma unroll
                for (int r = 0; r < 4; ++r) { p[r] = __expf(sa[is4][r]); lsum[is4] += p[r]; }
                int i_ = is4 * 16 + c15;
                *(int2*)(Pt + i_ * 128 + ((jg ^ (i_ & 7)) * 16) + (quad & 1) * 8) =
                    make_int2(pack2bf(p[0], p[1]), pack2bf(p[2], p[3]));
            }
        }
        __syncthreads();   // barrier 0: publish P0, drain V0 DMA

        for (int jt = 0; jt < 64; ++jt) {
            if (jt < 63) {
                int nb_ = (jt + 1) & 1;
                // (1) V-DMA for step jt+1 issued FIRST after barrier jt:
                //     slack = P-compute + consumer step before the drain
                const short* vs = vsg + (size_t)(jt + 1) * 64;
                char* vd = lds + nb_ * 32768 + w * 8192;
                #pragma unroll
                for (int r = 0; r < 8; ++r) gld16(vs + r * 8 * NN, vd + r * 1024);
                // (2) P(jt+1) -> Pbuf[nb_]
                f32x4 sa[4];
                #pragma unroll
                for (int is4 = 0; is4 < 4; ++is4)
                    sa[is4] = __builtin_amdgcn_mfma_f32_16x16x32_bf16(kf, qf[is4], initc, 0, 0, 0);
                kf = *(const bh8*)(kptr + (size_t)((jt + 2) & 63) * 2048);
                char* Pn = Pt + nb_ * 8192;
                int jg = w * 2 + (quad >> 1);
                #pragma unroll
                for (int is4 = 0; is4 < 4; ++is4) {
                    float p[4];
                    #pragma unroll
                    for (int r = 0; r < 4; ++r) { p[r] = __expf(sa[is4][r]); lsum[is4] += p[r]; }
                    int i_ = is4 * 16 + c15;
                    *(int2*)(Pn + i_ * 128 + ((jg ^ (i_ & 7)) * 16) + (quad & 1) * 8) =
                        make_int2(pack2bf(p[0], p[1]), pack2bf(p[2], p[3]));
                }
            }
            __syncthreads();
        }
        // softmax denominators: quad-reduce, publish per-producer partials
        #pragma unroll
        for (int is4 = 0; is4 < 4; ++is4) {
            lsum[is4] += __shfl_xor(lsum[is4], 16);
            lsum[is4] += __shfl_xor(lsum[is4], 32);
        }
        if (lane < 16) {
            #pragma unroll
            for (int is4 = 0; is4 < 4; ++is4)
                lred[w * 64 + is4 * 16 + lane] = lsum[is4];
        }
        __syncthreads();
        // producers done
    } else {
        // ================= consumer =================
        int cw = w - 4;                    // c-range [cw*64, cw*64+64)
        f32x16 a00, a01, a10, a11;
        #pragma unroll
        for (int r = 0; r < 16; ++r) { a00[r] = 0.f; a01[r] = 0.f; a10[r] = 0.f; a11[r] = 0.f; }

        __syncthreads();   // match producer barrier 0

        int swz = l31 & 7;
        int rowV0 = (cw * 64 + l31) * 128, rowV1 = rowV0 + 32 * 128;
        int rowP0 = l31 * 128, rowP1 = rowP0 + 32 * 128;
        for (int jt = 0; jt < 64; ++jt) {
            const char* Vb = lds + (jt & 1) * 32768;
            const char* Pc = Pt + (jt & 1) * 8192;
            #pragma unroll
            for (int kk = 0; kk < 4; ++kk) {
                int sl = ((kk * 2 + l5) ^ swz) * 16;
                bh8 va0 = *(const bh8*)(Vb + rowV0 + sl);
                bh8 va1 = *(const bh8*)(Vb + rowV1 + sl);
                bh8 pb0 = *(const bh8*)(Pc + rowP0 + sl);
                bh8 pb1 = *(const bh8*)(Pc + rowP1 + sl);
                a00 = __builtin_amdgcn_mfma_f32_32x32x16_bf16(va0, pb0, a00, 0, 0, 0);
                a01 = __builtin_amdgcn_mfma_f32_32x32x16_bf16(va0, pb1, a01, 0, 0, 0);
                a10 = __builtin_amdgcn_mfma_f32_32x32x16_bf16(va1, pb0, a10, 0, 0, 0);
                a11 = __builtin_amdgcn_mfma_f32_32x32x16_bf16(va1, pb1, a11, 0, 0, 0);
            }
            __syncthreads();
        }
        __syncthreads();   // match producer lred barrier

        // epilogue: O scale + residual + store (C/D 32x32: col=l31, row=(r&3)+8*(r>>2)+4*l5)
        float gm = gamma[0];
        const float* xb2 = x + (size_t)b * CC * NN;
        float* ob = out + (size_t)b * CC * NN;
        #pragma unroll
        for (int is = 0; is < 2; ++is) {
            int i_l = is * 32 + l31;
            float lt = lred[i_l] + lred[64 + i_l] + lred[128 + i_l] + lred[192 + i_l];
            float gl = gm / lt;
            int i = i0 + i_l;
            #pragma unroll
            for (int cs = 0; cs < 2; ++cs) {
                f32x16 av = (cs == 0) ? (is == 0 ? a00 : a01) : (is == 0 ? a10 : a11);
                #pragma unroll
                for (int r = 0; r < 16; ++r) {
                    int c = cw * 64 + cs * 32 + (r & 3) + 8 * (r >> 2) + 4 * l5;
                    ob[(size_t)c * NN + i] = gl * av[r] + xb2[(size_t)c * NN + i];
                }
            }
        }
    }
}

extern "C" void kernel_launch(void* const* d_in, const int* in_sizes, int n_in,
                              void* d_out, int out_size, void* d_ws, size_t ws_size,
                              hipStream_t stream) {
    const float* x     = (const float*)d_in[0];
    const float* Wq    = (const float*)d_in[1];
    const float* bq    = (const float*)d_in[2];
    const float* Wk    = (const float*)d_in[3];
    const float* bk    = (const float*)d_in[4];
    const float* Wv    = (const float*)d_in[5];
    const float* bv    = (const float*)d_in[6];
    const float* gamma = (const float*)d_in[7];
    float* out = (float*)d_out;
    char*  ws  = (char*)d_ws;
    short* Wpk  = (short*)(ws + WPK_OFF);
    float* ball = (float*)(ws + BALL_OFF);
    short* qbf  = (short*)(ws + QBF_OFF);
    short* kbf  = (short*)(ws + KBF_OFF);
    short* vbf  = (short*)(ws + VBF_OFF);

    prep_w<<<40, 256, 0, stream>>>(Wq, bq, Wk, bk, Wv, bv, Wpk, ball);
    proj<<<512, 256, 0, stream>>>(x, Wpk, ball, qbf, kbf, vbf);
    flash_attn<<<256, 512, 0, stream>>>(qbf, kbf, vbf, x, gamma, out);
}